// Round 5
// baseline (667.711 us; speedup 1.0000x reference)
//
#include <hip/hip_runtime.h>
#include <math.h>

#define DM   768
#define DI   1536
#define NDS  16
#define DTR  48
#define XDC  80
#define NB   2
#define SEQL 512
#define NT   (NB*SEQL)
#define CC   64
#define TT   8
#define BETA 0.9f
#define NSA  3.4445f
#define NSB  (-4.775f)
#define NSC  2.0315f
#define LOG2E 1.4426950408889634f

typedef __attribute__((ext_vector_type(8))) short short8v;
typedef __attribute__((ext_vector_type(4))) float f32x4;

__device__ __forceinline__ float silu_(float x){ return x / (1.f + __expf(-x)); }
__device__ __forceinline__ unsigned short bfr(float x){
  unsigned u = __float_as_uint(x);
  return (unsigned short)((u + 0x7fffu + ((u>>16)&1u)) >> 16);
}
__device__ __forceinline__ void gl_lds16(const unsigned short* g, unsigned short* l){
  __builtin_amdgcn_global_load_lds((const __attribute__((address_space(1))) void*)g,
                                   (__attribute__((address_space(3))) void*)l, 16, 0, 0);
}

// ---------------- rmsnorm: one block per token; BF=1 -> bf16 output ----------------
template<int BF>
__global__ void rms_k(const float* __restrict__ X, const float* __restrict__ W,
                      void* __restrict__ Ov)
{
  const int g = blockIdx.x, tid = threadIdx.x;
  const float* xr = X + (size_t)g*DM;
  float x0 = xr[tid], x1 = xr[tid+256], x2 = xr[tid+512];
  float ss = x0*x0 + x1*x1 + x2*x2;
  #pragma unroll
  for (int m=1; m<=32; m<<=1) ss += __shfl_xor(ss, m);
  __shared__ float ws[4];
  if ((tid & 63) == 0) ws[tid>>6] = ss;
  __syncthreads();
  float sc = rsqrtf((ws[0]+ws[1]+ws[2]+ws[3])*(1.f/DM) + 1e-5f);
  if (BF){
    unsigned short* o = (unsigned short*)Ov + (size_t)g*DM;
    o[tid]     = bfr(x0*sc*W[tid]);
    o[tid+256] = bfr(x1*sc*W[tid+256]);
    o[tid+512] = bfr(x2*sc*W[tid+512]);
  } else {
    float* o = (float*)Ov + (size_t)g*DM;
    o[tid]     = x0*sc*W[tid];
    o[tid+256] = x1*sc*W[tid+256];
    o[tid+512] = x2*sc*W[tid+512];
  }
}

// ---------------- f32 -> bf16 cast (vectorized) ----------------
__global__ void castbf_k(const float* __restrict__ in, unsigned short* __restrict__ out, int n4)
{
  const int i = blockIdx.x*256 + threadIdx.x;
  if (i >= n4) return;
  float4 v = ((const float4*)in)[i];
  ushort4 o;
  o.x = bfr(v.x); o.y = bfr(v.y); o.z = bfr(v.z); o.w = bfr(v.w);
  ((ushort4*)out)[i] = o;
}

__global__ void zero_k(float* __restrict__ p, int n)
{
  const int i = blockIdx.x*256 + threadIdx.x;
  if (i < n) p[i] = 0.f;
}

// ---------------- bf16 MFMA GEMM (m97 structure): C = A * B^T ----------------
// EPI: 0 direct store (SK==1), 3 atomicAdd (split-K, dst pre-initialized)
template<int EPI>
__global__ __launch_bounds__(256) void gemm_mf(
    const unsigned short* __restrict__ Abf, int lda,
    const unsigned short* __restrict__ Bbf, int ldb,
    float* __restrict__ Out,
    int M, int N, int K, int SK)
{
  __shared__ unsigned short As[128*32];
  __shared__ unsigned short Bs[128*32];
  const int tid  = threadIdx.x;
  const int wid  = tid >> 6, lane = tid & 63;
  const int bm   = blockIdx.y*128, bn = blockIdx.x*128;
  const int kc   = K/SK, kBeg = blockIdx.z*kc, kEnd = kBeg + kc;
  const int wr   = (wid>>1)*64, wc = (wid&1)*64;

  f32x4 acc[4][4];
  #pragma unroll
  for (int m=0;m<4;m++)
    #pragma unroll
    for (int n=0;n<4;n++) acc[m][n] = (f32x4){0.f,0.f,0.f,0.f};

  const int e0 = (wid*2)*512 + lane*8;
  const int e1 = e0 + 512;
  const int r0 = e0 >> 5, k0e = e0 & 31;
  const int r1 = e1 >> 5, k1e = e1 & 31;
  const unsigned short* Ag0 = Abf + (size_t)(bm + r0)*lda + k0e;
  const unsigned short* Ag1 = Abf + (size_t)(bm + r1)*lda + k1e;
  const unsigned short* Bg0 = Bbf + (size_t)(bn + r0)*ldb + k0e;
  const unsigned short* Bg1 = Bbf + (size_t)(bn + r1)*ldb + k1e;

  int aoff[4], boff[4];
  #pragma unroll
  for (int m=0;m<4;m++) aoff[m] = (wr + m*16 + (lane&15))*32 + (lane>>4)*8;
  #pragma unroll
  for (int n=0;n<4;n++) boff[n] = (wc + n*16 + (lane&15))*32 + (lane>>4)*8;

  for (int k0 = kBeg; k0 < kEnd; k0 += 32){
    gl_lds16(Ag0 + k0, As + e0);
    gl_lds16(Ag1 + k0, As + e1);
    gl_lds16(Bg0 + k0, Bs + e0);
    gl_lds16(Bg1 + k0, Bs + e1);
    __syncthreads();
    short8v af[4], bfv[4];
    #pragma unroll
    for (int m=0;m<4;m++) af[m]  = *(const short8v*)(As + aoff[m]);
    #pragma unroll
    for (int n=0;n<4;n++) bfv[n] = *(const short8v*)(Bs + boff[n]);
    #pragma unroll
    for (int m=0;m<4;m++)
      #pragma unroll
      for (int n=0;n<4;n++)
        acc[m][n] = __builtin_amdgcn_mfma_f32_16x16x32_bf16(af[m], bfv[n], acc[m][n], 0, 0, 0);
    __syncthreads();
  }

  #pragma unroll
  for (int m=0;m<4;m++){
    const int rowb = bm + wr + m*16 + (lane>>4)*4;
    #pragma unroll
    for (int n=0;n<4;n++){
      const int col = bn + wc + n*16 + (lane&15);
      #pragma unroll
      for (int r=0;r<4;r++){
        const int row = rowb + r;
        if (EPI==0) Out[(size_t)row*N + col] = acc[m][n][r];
        else        atomicAdd(&Out[(size_t)row*N + col], acc[m][n][r]);
      }
    }
  }
}

// ---------------- f32 GEMM (small shapes): C[r,c]=sum_k A[r*lda+k]*B[c*ldb+k] ----------------
// EPI: 1 softplus(x+bias[col]) direct, 3 atomicAdd (dst pre-zeroed)
template<int EPI>
__global__ void gemm64(const float* __restrict__ A, int lda,
                       const float* __restrict__ Bw, int ldb,
                       float* __restrict__ Out,
                       const float* __restrict__ aux,
                       int M, int N, int K, int SK)
{
  __shared__ float As[16][64], Bs[16][64];
  const int tid = threadIdx.x;
  const int bm = blockIdx.y*64, bn = blockIdx.x*64;
  const int kc = K/SK, kBeg = blockIdx.z*kc, kEnd = kBeg + kc;
  const int lr = tid>>2, lk = (tid&3)<<2;
  const int tx = tid&15, ty = tid>>4;
  float acc[4][4];
  #pragma unroll
  for (int i=0;i<4;i++)
    #pragma unroll
    for (int j=0;j<4;j++) acc[i][j] = 0.f;
  const float* Ap = A + (size_t)(bm+lr)*lda + lk;
  const bool bok = (bn+lr) < N;
  const float* Bp = Bw + (size_t)(bn+lr)*ldb + lk;
  for (int k0=kBeg; k0<kEnd; k0+=16){
    float4 a0 = *(const float4*)(Ap + k0);
    float4 b0 = {0,0,0,0};
    if (bok) b0 = *(const float4*)(Bp + k0);
    __syncthreads();
    As[lk+0][lr]=a0.x; As[lk+1][lr]=a0.y; As[lk+2][lr]=a0.z; As[lk+3][lr]=a0.w;
    Bs[lk+0][lr]=b0.x; Bs[lk+1][lr]=b0.y; Bs[lk+2][lr]=b0.z; Bs[lk+3][lr]=b0.w;
    __syncthreads();
    #pragma unroll
    for (int kk=0;kk<16;kk++){
      float a[4], b[4];
      *(float4*)a = *(const float4*)&As[kk][ty*4];
      *(float4*)b = *(const float4*)&Bs[kk][tx*4];
      #pragma unroll
      for (int i=0;i<4;i++)
        #pragma unroll
        for (int j=0;j<4;j++) acc[i][j] = fmaf(a[i], b[j], acc[i][j]);
    }
  }
  #pragma unroll
  for (int i=0;i<4;i++){
    const int row = bm + ty*4 + i;
    #pragma unroll
    for (int j=0;j<4;j++){
      const int col = bn + tx*4 + j;
      if (col < N){
        if (EPI==1){
          float vv = acc[i][j] + aux[col];
          vv = fmaxf(vv,0.f) + log1pf(__expf(-fabsf(vv)));
          Out[(size_t)row*N+col] = vv;
        } else {
          atomicAdd(&Out[(size_t)row*N+col], acc[i][j]);
        }
      }
    }
  }
}

// ---------------- causal depthwise conv (width 4) + bias + silu ----------------
__global__ void conv_k(const float* __restrict__ xz, const float* __restrict__ cw,
                       const float* __restrict__ cb, float* __restrict__ xc)
{
  const int d = blockIdx.x*256 + threadIdx.x;
  const int g = blockIdx.y;
  const int b = g >> 9, t = g & (SEQL-1);
  float4 w4 = *(const float4*)(cw + (size_t)d*4);
  const float wk[4] = {w4.x, w4.y, w4.z, w4.w};
  const float* col = xz + ((size_t)b*SEQL)*(2*DI) + d;
  float acc = cb[d];
  #pragma unroll
  for (int k=0;k<4;k++){
    int tt = t - 3 + k;
    if (tt >= 0) acc = fmaf(wk[k], col[(size_t)tt*(2*DI)], acc);
  }
  xc[(size_t)g*DI + d] = silu_(acc);
}

// ---------------- pass 1: per-chunk v aggregates + chunk dt sums ----------------
__global__ void vagg_k(const float* __restrict__ dt, const float* __restrict__ xcp,
                       const float* __restrict__ xdbl, float* __restrict__ Vagg,
                       float* __restrict__ S)
{
  const int d = blockIdx.x*256 + threadIdx.x;
  const int c = blockIdx.y, b = blockIdx.z;
  float acc[16];
  #pragma unroll
  for (int n=0;n<16;n++) acc[n] = 0.f;
  float sdt = 0.f;
  for (int s=0;s<TT;s++){
    const int g = b*SEQL + c*TT + s;
    float dv = dt[(size_t)g*DI + d];
    float w  = dv * xcp[(size_t)g*DI + d];
    sdt += dv;
    #pragma unroll
    for (int n=0;n<16;n++) acc[n] = fmaf(BETA, acc[n], w * xdbl[(size_t)g*XDC + 48 + n]);
  }
  const size_t base = ((size_t)(b*CC + c)*NDS)*DI + d;
  #pragma unroll
  for (int n=0;n<16;n++) Vagg[base + (size_t)n*DI] = acc[n];
  S[(size_t)(b*CC + c)*DI + d] = sdt;
}

// ---------------- pass 2: sequential-over-chunks combine for v_start ----------------
__global__ void vcomb_k(const float* __restrict__ Vagg, float* __restrict__ vst, float betaT)
{
  const int d = blockIdx.x*256 + threadIdx.x;
  const int n = blockIdx.y, b = blockIdx.z;
  const size_t stride = (size_t)NDS*DI;
  size_t idx = ((size_t)(b*CC)*NDS + n)*DI + d;
  float v = 0.f;
  for (int c=0;c<CC;c++){
    vst[idx] = v;
    v = fmaf(betaT, v, Vagg[idx]);
    idx += stride;
  }
}

// ---------------- gram_k: per-chunk reductions + full NS -> Qs matrices ----------------
// R0 = v0^T v0 (136), P0[n][s] = v0[:,n].w_s (128), G[r][s] = w_r.w_s (36)
// then R_s recurrence via closed-form p_s; Qs_s = (aI + b R/nu^2 + c R^2/nu^4)/nu
__device__ __forceinline__ int tri16(int i, int j){ return i*16 + j - ((i*(i+1))>>1); }

__global__ __launch_bounds__(512) void gram_k(
    const float* __restrict__ vst, const float* __restrict__ dt,
    const float* __restrict__ xcp, const float* __restrict__ xdbl,
    float* __restrict__ Qg)
{
  const int c = blockIdx.x, b = blockIdx.y;
  const int tid = threadIdx.x;
  const int lane = tid & 63, wid = tid >> 6;
  __shared__ float part[8][304];
  __shared__ float resv[304];
  __shared__ float sB[8][16];
  __shared__ float Rm[16][17];

  float v0[3][16];
  {
    const float* vs = vst + ((size_t)(b*CC + c)*NDS)*DI;
    #pragma unroll
    for (int j3=0;j3<3;j3++)
      #pragma unroll
      for (int n=0;n<16;n++) v0[j3][n] = vs[(size_t)n*DI + tid + j3*512];
  }
  float w[8][3];
  #pragma unroll
  for (int s=0;s<TT;s++){
    const size_t g = (size_t)(b*SEQL + c*TT + s);
    #pragma unroll
    for (int j3=0;j3<3;j3++){
      const size_t ii = g*DI + tid + j3*512;
      w[s][j3] = dt[ii] * xcp[ii];
    }
  }
  if (tid < 128){
    const int s = tid >> 4, n = tid & 15;
    sB[s][n] = xdbl[(size_t)(b*SEQL + c*TT + s)*XDC + 48 + n];
  }

  // batched reductions -> part[wave][idx]
  #pragma unroll
  for (int i2=0;i2<16;i2++){
    #pragma unroll
    for (int j2=i2;j2<16;j2++){
      float sR = v0[0][i2]*v0[0][j2];
      sR = fmaf(v0[1][i2], v0[1][j2], sR);
      sR = fmaf(v0[2][i2], v0[2][j2], sR);
      #pragma unroll
      for (int m=1;m<=32;m<<=1) sR += __shfl_xor(sR, m);
      if (lane == 0) part[wid][tri16(i2,j2)] = sR;
    }
  }
  #pragma unroll
  for (int n=0;n<16;n++){
    #pragma unroll
    for (int s=0;s<TT;s++){
      float sR = v0[0][n]*w[s][0];
      sR = fmaf(v0[1][n], w[s][1], sR);
      sR = fmaf(v0[2][n], w[s][2], sR);
      #pragma unroll
      for (int m=1;m<=32;m<<=1) sR += __shfl_xor(sR, m);
      if (lane == 0) part[wid][136 + n*8 + s] = sR;
    }
  }
  #pragma unroll
  for (int r=0;r<TT;r++){
    #pragma unroll
    for (int s=r;s<TT;s++){
      float sR = w[r][0]*w[s][0];
      sR = fmaf(w[r][1], w[s][1], sR);
      sR = fmaf(w[r][2], w[s][2], sR);
      #pragma unroll
      for (int m=1;m<=32;m<<=1) sR += __shfl_xor(sR, m);
      if (lane == 0) part[wid][264 + r*8 + s - ((r*(r+1))>>1)] = sR;
    }
  }
  __syncthreads();
  if (tid < 300){
    float a = 0.f;
    #pragma unroll
    for (int q=0;q<8;q++) a += part[q][tid];
    resv[tid] = a;
  }
  __syncthreads();

  // NS phase: 256 threads = full (i,j) matrix; R in register, recurrence over t
  const int i = tid >> 4, j = tid & 15;
  float Rreg = 0.f;
  if (tid < 256){
    const int lo = i < j ? i : j, hi = i < j ? j : i;
    Rreg = resv[tri16(lo,hi)];
  }
  constexpr float PB[9] = {1.f, 0.9f, 0.81f, 0.729f, 0.6561f, 0.59049f,
                           0.531441f, 0.4782969f, 0.43046721f};
  const size_t qbase = ((size_t)(b*CC + c)*TT)*256;
  #pragma unroll
  for (int t=0;t<TT;t++){
    if (tid < 256){
      float p_i = PB[t]*resv[136 + i*8 + t];
      float p_j = PB[t]*resv[136 + j*8 + t];
      #pragma unroll
      for (int r=0;r<t;r++){
        const float gg = resv[264 + r*8 + t - ((r*(r+1))>>1)];
        p_i = fmaf(PB[t-1-r]*gg, sB[r][i], p_i);
        p_j = fmaf(PB[t-1-r]*gg, sB[r][j], p_j);
      }
      const float bi = sB[t][i], bj = sB[t][j];
      const float gtt = resv[264 + t*8 + t - ((t*(t+1))>>1)];
      Rreg = BETA*BETA*Rreg + BETA*(p_i*bj + bi*p_j) + gtt*bi*bj;
      Rm[i][j] = Rreg;
    }
    __syncthreads();
    if (tid < 256){
      float tr = 0.f;
      #pragma unroll
      for (int k=0;k<16;k++) tr += Rm[k][k];
      const float nu = sqrtf(tr) + 1e-7f;
      const float inv_nu = 1.f/nu;
      const float inv2 = inv_nu*inv_nu;
      const float inv4 = inv2*inv2;
      float a2 = 0.f;
      #pragma unroll
      for (int k=0;k<16;k++) a2 = fmaf(Rm[i][k], Rm[k][j], a2);
      float q = NSB*inv2*Rreg + NSC*inv4*a2;
      if (i == j) q += NSA;
      Qg[qbase + t*256 + tid] = q * inv_nu;
    }
    __syncthreads();
  }
}

// ---------------- apply_k: barrier-free in-chunk scan, 1 d-row per thread ----------------
__global__ __launch_bounds__(256) void apply_k(
    const float* __restrict__ vst, const float* __restrict__ dt,
    const float* __restrict__ xcp, const float* __restrict__ xdbl,
    const float* __restrict__ Qg, const float* __restrict__ A_log,
    float* __restrict__ ylocal, float* __restrict__ hend)
{
  const int c = blockIdx.x, b = blockIdx.y, z = blockIdx.z;
  const int tid = threadIdx.x;
  const int d = z*256 + tid;
  __shared__ float sQ[8*256];
  __shared__ float sBC[8][32];

  const size_t qbase = ((size_t)(b*CC + c)*TT)*256;
  #pragma unroll
  for (int q=0;q<8;q++) sQ[q*256 + tid] = Qg[qbase + q*256 + tid];
  {
    const int s = tid >> 5, idx = tid & 31;
    sBC[s][idx] = xdbl[(size_t)(b*SEQL + c*TT + s)*XDC + 48 + idx];
  }
  __syncthreads();

  float v[16], h[16], Ar[16];
  {
    const float* vs = vst + ((size_t)(b*CC + c)*NDS)*DI + d;
    const float* arow = A_log + (size_t)d*NDS;
    #pragma unroll
    for (int n=0;n<16;n++){
      v[n] = vs[(size_t)n*DI];
      h[n] = 0.f;
      Ar[n] = -__expf(arow[n]) * LOG2E;
    }
  }

  for (int t=0;t<TT;t++){
    const size_t g = (size_t)(b*SEQL + c*TT + t);
    const float dtv = dt[g*DI + d];
    const float wv  = dtv * xcp[g*DI + d];
    #pragma unroll
    for (int n=0;n<16;n++) v[n] = fmaf(BETA, v[n], wv*sBC[t][n]);
    float un[16];
    #pragma unroll
    for (int n=0;n<16;n++) un[n] = 0.f;
    const float* qt = sQ + t*256;
    #pragma unroll
    for (int k=0;k<16;k++){
      const float vk = v[k];
      const float4 q0 = *(const float4*)(qt + k*16);
      const float4 q1 = *(const float4*)(qt + k*16 + 4);
      const float4 q2 = *(const float4*)(qt + k*16 + 8);
      const float4 q3 = *(const float4*)(qt + k*16 + 12);
      un[0]=fmaf(vk,q0.x,un[0]); un[1]=fmaf(vk,q0.y,un[1]); un[2]=fmaf(vk,q0.z,un[2]); un[3]=fmaf(vk,q0.w,un[3]);
      un[4]=fmaf(vk,q1.x,un[4]); un[5]=fmaf(vk,q1.y,un[5]); un[6]=fmaf(vk,q1.z,un[6]); un[7]=fmaf(vk,q1.w,un[7]);
      un[8]=fmaf(vk,q2.x,un[8]); un[9]=fmaf(vk,q2.y,un[9]); un[10]=fmaf(vk,q2.z,un[10]); un[11]=fmaf(vk,q2.w,un[11]);
      un[12]=fmaf(vk,q3.x,un[12]); un[13]=fmaf(vk,q3.y,un[13]); un[14]=fmaf(vk,q3.z,un[14]); un[15]=fmaf(vk,q3.w,un[15]);
    }
    float y = 0.f;
    #pragma unroll
    for (int n=0;n<16;n++){
      const float e = exp2f(dtv*Ar[n]);
      h[n] = fmaf(e, h[n], un[n]);
      y = fmaf(h[n], sBC[t][16+n], y);
    }
    ylocal[g*DI + d] = y;
  }
  float* he = hend + ((size_t)(b*CC + c)*NDS)*DI + d;
  #pragma unroll
  for (int n=0;n<16;n++) he[(size_t)n*DI] = h[n];
}

// ---------------- pass 4: combine h chunk-starts ----------------
__global__ void hcomb_k(const float* __restrict__ hend, const float* __restrict__ S,
                        const float* __restrict__ A_log, float* __restrict__ hst)
{
  const int d = blockIdx.x*256 + threadIdx.x;
  const int n = blockIdx.y, b = blockIdx.z;
  const float An = -__expf(A_log[(size_t)d*NDS + n]);
  const size_t stride = (size_t)NDS*DI;
  size_t idx  = ((size_t)(b*CC)*NDS + n)*DI + d;
  size_t sidx = (size_t)(b*CC)*DI + d;
  float hv = 0.f;
  for (int c=0;c<CC;c++){
    hst[idx] = hv;
    hv = fmaf(__expf(An * S[sidx]), hv, hend[idx]);
    idx += stride; sidx += DI;
  }
}

// ---------------- pass 5: y epilogue -> bf16 gated output ----------------
__global__ void yepi_k(const float* __restrict__ ylocal, const float* __restrict__ hst,
                       const float* __restrict__ dt, const float* __restrict__ xdbl,
                       const float* __restrict__ A_log, const float* __restrict__ Dv,
                       const float* __restrict__ xcp, const float* __restrict__ xz,
                       unsigned short* __restrict__ ybf)
{
  const int d = blockIdx.x*256 + threadIdx.x;
  const int g = blockIdx.y;
  const int b = g >> 9, t = g & (SEQL-1);
  const int c = t / TT, s0 = c*TT;
  float ddt = 0.f;
  for (int r=s0; r<=t; r++) ddt += dt[(size_t)(b*SEQL + r)*DI + d];
  const float* hs = hst + ((size_t)(b*CC + c)*NDS)*DI + d;
  const float* ar = A_log + (size_t)d*NDS;
  float corr = 0.f;
  #pragma unroll
  for (int n=0;n<16;n++){
    float An = -__expf(ar[n]);
    float Cn = xdbl[(size_t)g*XDC + 64 + n];
    corr = fmaf(hs[(size_t)n*DI] * __expf(An*ddt), Cn, corr);
  }
  float y = ylocal[(size_t)g*DI + d] + corr + Dv[d]*xcp[(size_t)g*DI + d];
  float z = xz[(size_t)g*(2*DI) + DI + d];
  ybf[(size_t)g*DI + d] = bfr(y * silu_(z));
}

// ============================== host ==============================
extern "C" void kernel_launch(void* const* d_in, const int* in_sizes, int n_in,
                              void* d_out, int out_size, void* d_ws, size_t ws_size,
                              hipStream_t stream)
{
  (void)in_sizes; (void)n_in; (void)out_size; (void)ws_size;
  const float* x      = (const float*)d_in[0];
  const float* in_w   = (const float*)d_in[1];
  const float* conv_w = (const float*)d_in[2];
  const float* conv_b = (const float*)d_in[3];
  const float* xp_w   = (const float*)d_in[4];
  const float* dtp_w  = (const float*)d_in[5];
  const float* dtp_b  = (const float*)d_in[6];
  const float* A_log  = (const float*)d_in[7];
  const float* Dp     = (const float*)d_in[8];
  const float* out_w  = (const float*)d_in[9];
  const float* norm_w = (const float*)d_in[10];
  const float* fnorm  = (const float*)d_in[11];

  const float betaT = powf(BETA, (float)TT);

  float* w0 = (float*)d_ws; size_t off = 0;
  auto alloc = [&](size_t n)->float*{ float* p = w0 + off; off += (n + 63) & ~(size_t)63; return p; };
  float* xa     = alloc((size_t)NT*DM);
  float* xb     = alloc((size_t)NT*DM);
  float* bfA    = alloc((size_t)NT*DI/2);       // bf16 A-matrices (xnb then ybf)
  float* xz     = alloc((size_t)NT*2*DI);
  float* xcb    = alloc((size_t)NT*DI);
  float* xdbl   = alloc((size_t)NT*XDC);
  float* dtb    = alloc((size_t)NT*DI);
  float* ylocal = alloc((size_t)NT*DI);
  float* Sbuf   = alloc((size_t)NB*CC*DI);
  float* Qg     = alloc((size_t)NB*CC*TT*256);
  float* big1   = alloc((size_t)NB*CC*NDS*DI);  // Vagg / hend
  float* big2   = alloc((size_t)NB*CC*NDS*DI);  // wbf / vst / hst

  unsigned short* xnb = (unsigned short*)bfA;   // [NT][DM]
  unsigned short* ybf = (unsigned short*)bfA;   // [NT][DI]
  unsigned short* wbf = (unsigned short*)big2;  // bf16 weights (dead before vcomb writes)

  const float* xcur = x;
  float* nxt = xa;
  for (int l=0; l<2; l++){
    const float* inw_l = in_w   + (size_t)l*2*DI*DM;
    const float* cw_l  = conv_w + (size_t)l*DI*4;
    const float* cb_l  = conv_b + (size_t)l*DI;
    const float* xpw_l = xp_w   + (size_t)l*XDC*DI;
    const float* dtw_l = dtp_w  + (size_t)l*DI*DTR;
    const float* dtbi  = dtp_b  + (size_t)l*DI;
    const float* al_l  = A_log  + (size_t)l*DI*NDS;
    const float* d_l   = Dp     + (size_t)l*DI;
    const float* ow_l  = out_w  + (size_t)l*DM*DI;
    const float* nw_l  = norm_w + (size_t)l*DM;

    castbf_k<<<dim3((2*DI*DM/4+255)/256), dim3(256), 0, stream>>>(inw_l, wbf, 2*DI*DM/4);
    rms_k<1><<<dim3(NT), dim3(256), 0, stream>>>(xcur, nw_l, xnb);
    gemm_mf<0><<<dim3(2*DI/128, NT/128, 1), dim3(256), 0, stream>>>(
        xnb, DM, wbf, DM, xz, NT, 2*DI, DM, 1);
    conv_k<<<dim3(DI/256, NT), dim3(256), 0, stream>>>(xz, cw_l, cb_l, xcb);
    zero_k<<<dim3((NT*XDC+255)/256), dim3(256), 0, stream>>>(xdbl, NT*XDC);
    gemm64<3><<<dim3((XDC+63)/64, NT/64, 8), dim3(256), 0, stream>>>(
        xcb, DI, xpw_l, DI, xdbl, nullptr, NT, XDC, DI, 8);
    gemm64<1><<<dim3(DI/64, NT/64, 1), dim3(256), 0, stream>>>(
        xdbl, XDC, dtw_l, DTR, dtb, dtbi, NT, DI, DTR, 1);
    vagg_k<<<dim3(DI/256, CC, NB), dim3(256), 0, stream>>>(dtb, xcb, xdbl, big1, Sbuf);
    vcomb_k<<<dim3(DI/256, NDS, NB), dim3(256), 0, stream>>>(big1, big2, betaT);
    gram_k<<<dim3(CC, NB), dim3(512), 0, stream>>>(big2, dtb, xcb, xdbl, Qg);
    apply_k<<<dim3(CC, NB, DI/256), dim3(256), 0, stream>>>(
        big2, dtb, xcb, xdbl, Qg, al_l, ylocal, big1);
    hcomb_k<<<dim3(DI/256, NDS, NB), dim3(256), 0, stream>>>(big1, Sbuf, al_l, big2);
    yepi_k<<<dim3(DI/256, NT), dim3(256), 0, stream>>>(ylocal, big2, dtb, xdbl, al_l, d_l, xcb, xz, ybf);
    castbf_k<<<dim3((DM*DI/4+255)/256), dim3(256), 0, stream>>>(ow_l, wbf, DM*DI/4);
    hipMemcpyAsync(nxt, xcur, (size_t)NT*DM*sizeof(float), hipMemcpyDeviceToDevice, stream);
    gemm_mf<3><<<dim3(DM/128, NT/128, 8), dim3(256), 0, stream>>>(
        ybf, DI, wbf, DI, nxt, NT, DM, DI, 8);
    xcur = nxt; nxt = xb;
  }
  rms_k<0><<<dim3(NT), dim3(256), 0, stream>>>(xcur, fnorm, (float*)d_out);
}

// Round 6
// 542.574 us; speedup vs baseline: 1.2306x; 1.2306x over previous
//
#include <hip/hip_runtime.h>
#include <math.h>

#define DM   768
#define DI   1536
#define NDS  16
#define DTR  48
#define XDC  80
#define NB   2
#define SEQL 512
#define NT   (NB*SEQL)
#define CC   64
#define TT   8
#define BETA 0.9f
#define NSA  3.4445f
#define NSB  (-4.775f)
#define NSC  2.0315f
#define LOG2E 1.4426950408889634f

typedef __attribute__((ext_vector_type(8))) short short8v;
typedef __attribute__((ext_vector_type(4))) float f32x4;

__device__ __forceinline__ float silu_(float x){ return x / (1.f + __expf(-x)); }
__device__ __forceinline__ unsigned short bfr(float x){
  unsigned u = __float_as_uint(x);
  return (unsigned short)((u + 0x7fffu + ((u>>16)&1u)) >> 16);
}
__device__ __forceinline__ void gl_lds16(const unsigned short* g, unsigned short* l){
  __builtin_amdgcn_global_load_lds((const __attribute__((address_space(1))) void*)g,
                                   (__attribute__((address_space(3))) void*)l, 16, 0, 0);
}

// ---------------- rmsnorm: one block per token; BF=1 -> bf16 output ----------------
template<int BF>
__global__ void rms_k(const float* __restrict__ X, const float* __restrict__ W,
                      void* __restrict__ Ov)
{
  const int g = blockIdx.x, tid = threadIdx.x;
  const float* xr = X + (size_t)g*DM;
  float x0 = xr[tid], x1 = xr[tid+256], x2 = xr[tid+512];
  float ss = x0*x0 + x1*x1 + x2*x2;
  #pragma unroll
  for (int m=1; m<=32; m<<=1) ss += __shfl_xor(ss, m);
  __shared__ float ws[4];
  if ((tid & 63) == 0) ws[tid>>6] = ss;
  __syncthreads();
  float sc = rsqrtf((ws[0]+ws[1]+ws[2]+ws[3])*(1.f/DM) + 1e-5f);
  if (BF){
    unsigned short* o = (unsigned short*)Ov + (size_t)g*DM;
    o[tid]     = bfr(x0*sc*W[tid]);
    o[tid+256] = bfr(x1*sc*W[tid+256]);
    o[tid+512] = bfr(x2*sc*W[tid+512]);
  } else {
    float* o = (float*)Ov + (size_t)g*DM;
    o[tid]     = x0*sc*W[tid];
    o[tid+256] = x1*sc*W[tid+256];
    o[tid+512] = x2*sc*W[tid+512];
  }
}

// ---------------- f32 -> bf16 cast (vectorized) ----------------
__global__ void castbf_k(const float* __restrict__ in, unsigned short* __restrict__ out, int n4)
{
  const int i = blockIdx.x*256 + threadIdx.x;
  if (i >= n4) return;
  float4 v = ((const float4*)in)[i];
  ushort4 o;
  o.x = bfr(v.x); o.y = bfr(v.y); o.z = bfr(v.z); o.w = bfr(v.w);
  ((ushort4*)out)[i] = o;
}

// ---------------- bf16 MFMA GEMM (m97 structure): C = A * B^T ----------------
// EPI: 0 none. SK>1 -> Part[z*M*N + r*N+c].
template<int EPI>
__global__ __launch_bounds__(256) void gemm_mf(
    const unsigned short* __restrict__ Abf, int lda,
    const unsigned short* __restrict__ Bbf, int ldb,
    float* __restrict__ Out, float* __restrict__ Part,
    int M, int N, int K, int SK)
{
  __shared__ unsigned short As[128*32];
  __shared__ unsigned short Bs[128*32];
  const int tid  = threadIdx.x;
  const int wid  = tid >> 6, lane = tid & 63;
  const int bm   = blockIdx.y*128, bn = blockIdx.x*128;
  const int kc   = K/SK, kBeg = blockIdx.z*kc, kEnd = kBeg + kc;
  const int wr   = (wid>>1)*64, wc = (wid&1)*64;

  f32x4 acc[4][4];
  #pragma unroll
  for (int m=0;m<4;m++)
    #pragma unroll
    for (int n=0;n<4;n++) acc[m][n] = (f32x4){0.f,0.f,0.f,0.f};

  const int e0 = (wid*2)*512 + lane*8;
  const int e1 = e0 + 512;
  const int r0 = e0 >> 5, k0e = e0 & 31;
  const int r1 = e1 >> 5, k1e = e1 & 31;
  const unsigned short* Ag0 = Abf + (size_t)(bm + r0)*lda + k0e;
  const unsigned short* Ag1 = Abf + (size_t)(bm + r1)*lda + k1e;
  const unsigned short* Bg0 = Bbf + (size_t)(bn + r0)*ldb + k0e;
  const unsigned short* Bg1 = Bbf + (size_t)(bn + r1)*ldb + k1e;

  int aoff[4], boff[4];
  #pragma unroll
  for (int m=0;m<4;m++) aoff[m] = (wr + m*16 + (lane&15))*32 + (lane>>4)*8;
  #pragma unroll
  for (int n=0;n<4;n++) boff[n] = (wc + n*16 + (lane&15))*32 + (lane>>4)*8;

  for (int k0 = kBeg; k0 < kEnd; k0 += 32){
    gl_lds16(Ag0 + k0, As + e0);
    gl_lds16(Ag1 + k0, As + e1);
    gl_lds16(Bg0 + k0, Bs + e0);
    gl_lds16(Bg1 + k0, Bs + e1);
    __syncthreads();
    short8v af[4], bfv[4];
    #pragma unroll
    for (int m=0;m<4;m++) af[m]  = *(const short8v*)(As + aoff[m]);
    #pragma unroll
    for (int n=0;n<4;n++) bfv[n] = *(const short8v*)(Bs + boff[n]);
    #pragma unroll
    for (int m=0;m<4;m++)
      #pragma unroll
      for (int n=0;n<4;n++)
        acc[m][n] = __builtin_amdgcn_mfma_f32_16x16x32_bf16(af[m], bfv[n], acc[m][n], 0, 0, 0);
    __syncthreads();
  }

  #pragma unroll
  for (int m=0;m<4;m++){
    const int rowb = bm + wr + m*16 + (lane>>4)*4;
    #pragma unroll
    for (int n=0;n<4;n++){
      const int col = bn + wc + n*16 + (lane&15);
      #pragma unroll
      for (int r=0;r<4;r++){
        const int row = rowb + r;
        if (SK == 1) Out[(size_t)row*N + col] = acc[m][n][r];
        else         Part[(size_t)blockIdx.z*M*N + (size_t)row*N + col] = acc[m][n][r];
      }
    }
  }
}

// ---------------- f32 GEMM (small shapes): C[r,c]=sum_k A[r*lda+k]*B[c*ldb+k] ----------------
// EPI: 0 none, 1 softplus(x+bias[col]).  SK>1 -> Part.
template<int EPI>
__global__ void gemm64(const float* __restrict__ A, int lda,
                       const float* __restrict__ Bw, int ldb,
                       float* __restrict__ Out, float* __restrict__ Part,
                       const float* __restrict__ aux,
                       int M, int N, int K, int SK)
{
  __shared__ float As[16][64], Bs[16][64];
  const int tid = threadIdx.x;
  const int bm = blockIdx.y*64, bn = blockIdx.x*64;
  const int kc = K/SK, kBeg = blockIdx.z*kc, kEnd = kBeg + kc;
  const int lr = tid>>2, lk = (tid&3)<<2;
  const int tx = tid&15, ty = tid>>4;
  float acc[4][4];
  #pragma unroll
  for (int i=0;i<4;i++)
    #pragma unroll
    for (int j=0;j<4;j++) acc[i][j] = 0.f;
  const float* Ap = A + (size_t)(bm+lr)*lda + lk;
  const bool bok = (bn+lr) < N;
  const float* Bp = Bw + (size_t)(bn+lr)*ldb + lk;
  for (int k0=kBeg; k0<kEnd; k0+=16){
    float4 a0 = *(const float4*)(Ap + k0);
    float4 b0 = {0,0,0,0};
    if (bok) b0 = *(const float4*)(Bp + k0);
    __syncthreads();
    As[lk+0][lr]=a0.x; As[lk+1][lr]=a0.y; As[lk+2][lr]=a0.z; As[lk+3][lr]=a0.w;
    Bs[lk+0][lr]=b0.x; Bs[lk+1][lr]=b0.y; Bs[lk+2][lr]=b0.z; Bs[lk+3][lr]=b0.w;
    __syncthreads();
    #pragma unroll
    for (int kk=0;kk<16;kk++){
      float a[4], b[4];
      *(float4*)a = *(const float4*)&As[kk][ty*4];
      *(float4*)b = *(const float4*)&Bs[kk][tx*4];
      #pragma unroll
      for (int i=0;i<4;i++)
        #pragma unroll
        for (int j=0;j<4;j++) acc[i][j] = fmaf(a[i], b[j], acc[i][j]);
    }
  }
  #pragma unroll
  for (int i=0;i<4;i++){
    const int row = bm + ty*4 + i;
    #pragma unroll
    for (int j=0;j<4;j++){
      const int col = bn + tx*4 + j;
      if (col < N){
        if (SK == 1){
          float vv = acc[i][j];
          if (EPI==1){ vv += aux[col]; vv = fmaxf(vv,0.f) + log1pf(__expf(-fabsf(vv))); }
          Out[(size_t)row*N+col] = vv;
        } else {
          Part[(size_t)blockIdx.z*M*N + (size_t)row*N+col] = acc[i][j];
        }
      }
    }
  }
}

// EPI: 0 plain sum, 2 sum + aux[i] (residual)
template<int EPI>
__global__ void reduce_k(const float* __restrict__ Part, float* __restrict__ Out,
                         const float* __restrict__ aux, int MN, int SK)
{
  const int i = blockIdx.x*256 + threadIdx.x;
  if (i >= MN) return;
  float s = 0.f;
  for (int z=0; z<SK; z++) s += Part[(size_t)z*MN + i];
  if (EPI==2) s += aux[i];
  Out[i] = s;
}

// ---------------- causal depthwise conv (width 4) + bias + silu ----------------
__global__ void conv_k(const float* __restrict__ xz, const float* __restrict__ cw,
                       const float* __restrict__ cb, float* __restrict__ xc)
{
  const int d = blockIdx.x*256 + threadIdx.x;
  const int g = blockIdx.y;
  const int b = g >> 9, t = g & (SEQL-1);
  float4 w4 = *(const float4*)(cw + (size_t)d*4);
  const float wk[4] = {w4.x, w4.y, w4.z, w4.w};
  const float* col = xz + ((size_t)b*SEQL)*(2*DI) + d;
  float acc = cb[d];
  #pragma unroll
  for (int k=0;k<4;k++){
    int tt = t - 3 + k;
    if (tt >= 0) acc = fmaf(wk[k], col[(size_t)tt*(2*DI)], acc);
  }
  xc[(size_t)g*DI + d] = silu_(acc);
}

// ---------------- pass 1: per-chunk v aggregates + chunk dt sums ----------------
__global__ void vagg_k(const float* __restrict__ dt, const float* __restrict__ xcp,
                       const float* __restrict__ xdbl, float* __restrict__ Vagg,
                       float* __restrict__ S)
{
  const int d = blockIdx.x*256 + threadIdx.x;
  const int c = blockIdx.y, b = blockIdx.z;
  float acc[16];
  #pragma unroll
  for (int n=0;n<16;n++) acc[n] = 0.f;
  float sdt = 0.f;
  for (int s=0;s<TT;s++){
    const int g = b*SEQL + c*TT + s;
    float dv = dt[(size_t)g*DI + d];
    float w  = dv * xcp[(size_t)g*DI + d];
    sdt += dv;
    #pragma unroll
    for (int n=0;n<16;n++) acc[n] = fmaf(BETA, acc[n], w * xdbl[(size_t)g*XDC + 48 + n]);
  }
  const size_t base = ((size_t)(b*CC + c)*NDS)*DI + d;
  #pragma unroll
  for (int n=0;n<16;n++) Vagg[base + (size_t)n*DI] = acc[n];
  S[(size_t)(b*CC + c)*DI + d] = sdt;
}

// ---------------- pass 2: sequential-over-chunks combine for v_start ----------------
__global__ void vcomb_k(const float* __restrict__ Vagg, float* __restrict__ vst, float betaT)
{
  const int d = blockIdx.x*256 + threadIdx.x;
  const int n = blockIdx.y, b = blockIdx.z;
  const size_t stride = (size_t)NDS*DI;
  size_t idx = ((size_t)(b*CC)*NDS + n)*DI + d;
  float v = 0.f;
  for (int c=0;c<CC;c++){
    vst[idx] = v;
    v = fmaf(betaT, v, Vagg[idx]);
    idx += stride;
  }
}

// ---------------- gram_k: per-chunk reductions + full NS -> Qs matrices ----------------
// R0 = v0^T v0 (136), P0[n][s] = v0[:,n].w_s (128), G[r][s] = w_r.w_s (36)
// then R_t recurrence via closed-form p_t; Q_t = (aI + b R/nu^2 + c R^2/nu^4)/nu
__device__ __forceinline__ int tri16(int i, int j){ return i*16 + j - ((i*(i+1))>>1); }

__global__ __launch_bounds__(512,1) void gram_k(
    const float* __restrict__ vst, const float* __restrict__ dt,
    const float* __restrict__ xcp, const float* __restrict__ xdbl,
    float* __restrict__ Qg)
{
  const int c = blockIdx.x, b = blockIdx.y;
  const int tid = threadIdx.x;
  const int lane = tid & 63, wid = tid >> 6;
  __shared__ float part[8][304];
  __shared__ float resv[304];
  __shared__ float sB[8][16];
  __shared__ float Rm[16][17];

  float v0[3][16];
  {
    const float* vs = vst + ((size_t)(b*CC + c)*NDS)*DI;
    #pragma unroll
    for (int j3=0;j3<3;j3++)
      #pragma unroll
      for (int n=0;n<16;n++) v0[j3][n] = vs[(size_t)n*DI + tid + j3*512];
  }
  float w[8][3];
  #pragma unroll
  for (int s=0;s<TT;s++){
    const size_t g = (size_t)(b*SEQL + c*TT + s);
    #pragma unroll
    for (int j3=0;j3<3;j3++){
      const size_t ii = g*DI + tid + j3*512;
      w[s][j3] = dt[ii] * xcp[ii];
    }
  }
  if (tid < 128){
    const int s = tid >> 4, n = tid & 15;
    sB[s][n] = xdbl[(size_t)(b*SEQL + c*TT + s)*XDC + 48 + n];
  }

  // batched reductions -> part[wave][idx]
  #pragma unroll
  for (int i2=0;i2<16;i2++){
    #pragma unroll
    for (int j2=i2;j2<16;j2++){
      float sR = v0[0][i2]*v0[0][j2];
      sR = fmaf(v0[1][i2], v0[1][j2], sR);
      sR = fmaf(v0[2][i2], v0[2][j2], sR);
      #pragma unroll
      for (int m=1;m<=32;m<<=1) sR += __shfl_xor(sR, m);
      if (lane == 0) part[wid][tri16(i2,j2)] = sR;
    }
  }
  #pragma unroll
  for (int n=0;n<16;n++){
    #pragma unroll
    for (int s=0;s<TT;s++){
      float sR = v0[0][n]*w[s][0];
      sR = fmaf(v0[1][n], w[s][1], sR);
      sR = fmaf(v0[2][n], w[s][2], sR);
      #pragma unroll
      for (int m=1;m<=32;m<<=1) sR += __shfl_xor(sR, m);
      if (lane == 0) part[wid][136 + n*8 + s] = sR;
    }
  }
  #pragma unroll
  for (int r=0;r<TT;r++){
    #pragma unroll
    for (int s=r;s<TT;s++){
      float sR = w[r][0]*w[s][0];
      sR = fmaf(w[r][1], w[s][1], sR);
      sR = fmaf(w[r][2], w[s][2], sR);
      #pragma unroll
      for (int m=1;m<=32;m<<=1) sR += __shfl_xor(sR, m);
      if (lane == 0) part[wid][264 + r*8 + s - ((r*(r+1))>>1)] = sR;
    }
  }
  __syncthreads();
  if (tid < 300){
    float a = 0.f;
    #pragma unroll
    for (int q=0;q<8;q++) a += part[q][tid];
    resv[tid] = a;
  }
  __syncthreads();

  // NS phase: 256 threads = full (i,j) matrix; R in register, recurrence over t
  const int i = tid >> 4, j = tid & 15;
  float Rreg = 0.f;
  if (tid < 256){
    const int lo = i < j ? i : j, hi = i < j ? j : i;
    Rreg = resv[tri16(lo,hi)];
  }
  constexpr float PB[9] = {1.f, 0.9f, 0.81f, 0.729f, 0.6561f, 0.59049f,
                           0.531441f, 0.4782969f, 0.43046721f};
  const size_t qbase = ((size_t)(b*CC + c)*TT)*256;
  #pragma unroll
  for (int t=0;t<TT;t++){
    if (tid < 256){
      float p_i = PB[t]*resv[136 + i*8 + t];
      float p_j = PB[t]*resv[136 + j*8 + t];
      #pragma unroll
      for (int r=0;r<t;r++){
        const float gg = resv[264 + r*8 + t - ((r*(r+1))>>1)];
        p_i = fmaf(PB[t-1-r]*gg, sB[r][i], p_i);
        p_j = fmaf(PB[t-1-r]*gg, sB[r][j], p_j);
      }
      const float bi = sB[t][i], bj = sB[t][j];
      const float gtt = resv[264 + t*8 + t - ((t*(t+1))>>1)];
      Rreg = BETA*BETA*Rreg + BETA*(p_i*bj + bi*p_j) + gtt*bi*bj;
      Rm[i][j] = Rreg;
    }
    __syncthreads();
    if (tid < 256){
      float tr = 0.f;
      #pragma unroll
      for (int k=0;k<16;k++) tr += Rm[k][k];
      const float nu = sqrtf(tr) + 1e-7f;
      const float inv_nu = 1.f/nu;
      const float inv2 = inv_nu*inv_nu;
      const float inv4 = inv2*inv2;
      float a2 = 0.f;
      #pragma unroll
      for (int k=0;k<16;k++) a2 = fmaf(Rm[i][k], Rm[k][j], a2);
      float q = NSB*inv2*Rreg + NSC*inv4*a2;
      if (i == j) q += NSA;
      Qg[qbase + t*256 + tid] = q * inv_nu;
    }
    __syncthreads();
  }
}

// ---------------- apply_k: barrier-free in-chunk scan, 1 d-row per thread ----------------
__global__ __launch_bounds__(256) void apply_k(
    const float* __restrict__ vst, const float* __restrict__ dt,
    const float* __restrict__ xcp, const float* __restrict__ xdbl,
    const float* __restrict__ Qg, const float* __restrict__ A_log,
    float* __restrict__ ylocal, float* __restrict__ hend)
{
  const int c = blockIdx.x, b = blockIdx.y, z = blockIdx.z;
  const int tid = threadIdx.x;
  const int d = z*256 + tid;
  __shared__ float sQ[8*256];
  __shared__ float sBC[8][32];

  const size_t qbase = ((size_t)(b*CC + c)*TT)*256;
  #pragma unroll
  for (int q=0;q<8;q++) sQ[q*256 + tid] = Qg[qbase + q*256 + tid];
  {
    const int s = tid >> 5, idx = tid & 31;
    sBC[s][idx] = xdbl[(size_t)(b*SEQL + c*TT + s)*XDC + 48 + idx];
  }
  __syncthreads();

  float v[16], h[16], Ar[16];
  {
    const float* vs = vst + ((size_t)(b*CC + c)*NDS)*DI + d;
    const float* arow = A_log + (size_t)d*NDS;
    #pragma unroll
    for (int n=0;n<16;n++){
      v[n] = vs[(size_t)n*DI];
      h[n] = 0.f;
      Ar[n] = -__expf(arow[n]) * LOG2E;
    }
  }

  for (int t=0;t<TT;t++){
    const size_t g = (size_t)(b*SEQL + c*TT + t);
    const float dtv = dt[g*DI + d];
    const float wv  = dtv * xcp[g*DI + d];
    #pragma unroll
    for (int n=0;n<16;n++) v[n] = fmaf(BETA, v[n], wv*sBC[t][n]);
    float un[16];
    #pragma unroll
    for (int n=0;n<16;n++) un[n] = 0.f;
    const float* qt = sQ + t*256;
    #pragma unroll
    for (int k=0;k<16;k++){
      const float vk = v[k];
      const float4 q0 = *(const float4*)(qt + k*16);
      const float4 q1 = *(const float4*)(qt + k*16 + 4);
      const float4 q2 = *(const float4*)(qt + k*16 + 8);
      const float4 q3 = *(const float4*)(qt + k*16 + 12);
      un[0]=fmaf(vk,q0.x,un[0]); un[1]=fmaf(vk,q0.y,un[1]); un[2]=fmaf(vk,q0.z,un[2]); un[3]=fmaf(vk,q0.w,un[3]);
      un[4]=fmaf(vk,q1.x,un[4]); un[5]=fmaf(vk,q1.y,un[5]); un[6]=fmaf(vk,q1.z,un[6]); un[7]=fmaf(vk,q1.w,un[7]);
      un[8]=fmaf(vk,q2.x,un[8]); un[9]=fmaf(vk,q2.y,un[9]); un[10]=fmaf(vk,q2.z,un[10]); un[11]=fmaf(vk,q2.w,un[11]);
      un[12]=fmaf(vk,q3.x,un[12]); un[13]=fmaf(vk,q3.y,un[13]); un[14]=fmaf(vk,q3.z,un[14]); un[15]=fmaf(vk,q3.w,un[15]);
    }
    float y = 0.f;
    #pragma unroll
    for (int n=0;n<16;n++){
      const float e = exp2f(dtv*Ar[n]);
      h[n] = fmaf(e, h[n], un[n]);
      y = fmaf(h[n], sBC[t][16+n], y);
    }
    ylocal[g*DI + d] = y;
  }
  float* he = hend + ((size_t)(b*CC + c)*NDS)*DI + d;
  #pragma unroll
  for (int n=0;n<16;n++) he[(size_t)n*DI] = h[n];
}

// ---------------- pass 4: combine h chunk-starts ----------------
__global__ void hcomb_k(const float* __restrict__ hend, const float* __restrict__ S,
                        const float* __restrict__ A_log, float* __restrict__ hst)
{
  const int d = blockIdx.x*256 + threadIdx.x;
  const int n = blockIdx.y, b = blockIdx.z;
  const float An = -__expf(A_log[(size_t)d*NDS + n]);
  const size_t stride = (size_t)NDS*DI;
  size_t idx  = ((size_t)(b*CC)*NDS + n)*DI + d;
  size_t sidx = (size_t)(b*CC)*DI + d;
  float hv = 0.f;
  for (int c=0;c<CC;c++){
    hst[idx] = hv;
    hv = fmaf(__expf(An * S[sidx]), hv, hend[idx]);
    idx += stride; sidx += DI;
  }
}

// ---------------- pass 5: y epilogue -> bf16 gated output ----------------
__global__ void yepi_k(const float* __restrict__ ylocal, const float* __restrict__ hst,
                       const float* __restrict__ dt, const float* __restrict__ xdbl,
                       const float* __restrict__ A_log, const float* __restrict__ Dv,
                       const float* __restrict__ xcp, const float* __restrict__ xz,
                       unsigned short* __restrict__ ybf)
{
  const int d = blockIdx.x*256 + threadIdx.x;
  const int g = blockIdx.y;
  const int b = g >> 9, t = g & (SEQL-1);
  const int c = t / TT, s0 = c*TT;
  float ddt = 0.f;
  for (int r=s0; r<=t; r++) ddt += dt[(size_t)(b*SEQL + r)*DI + d];
  const float* hs = hst + ((size_t)(b*CC + c)*NDS)*DI + d;
  const float* ar = A_log + (size_t)d*NDS;
  float corr = 0.f;
  #pragma unroll
  for (int n=0;n<16;n++){
    float An = -__expf(ar[n]);
    float Cn = xdbl[(size_t)g*XDC + 64 + n];
    corr = fmaf(hs[(size_t)n*DI] * __expf(An*ddt), Cn, corr);
  }
  float y = ylocal[(size_t)g*DI + d] + corr + Dv[d]*xcp[(size_t)g*DI + d];
  float z = xz[(size_t)g*(2*DI) + DI + d];
  ybf[(size_t)g*DI + d] = bfr(y * silu_(z));
}

// ============================== host ==============================
extern "C" void kernel_launch(void* const* d_in, const int* in_sizes, int n_in,
                              void* d_out, int out_size, void* d_ws, size_t ws_size,
                              hipStream_t stream)
{
  (void)in_sizes; (void)n_in; (void)out_size; (void)ws_size;
  const float* x      = (const float*)d_in[0];
  const float* in_w   = (const float*)d_in[1];
  const float* conv_w = (const float*)d_in[2];
  const float* conv_b = (const float*)d_in[3];
  const float* xp_w   = (const float*)d_in[4];
  const float* dtp_w  = (const float*)d_in[5];
  const float* dtp_b  = (const float*)d_in[6];
  const float* A_log  = (const float*)d_in[7];
  const float* Dp     = (const float*)d_in[8];
  const float* out_w  = (const float*)d_in[9];
  const float* norm_w = (const float*)d_in[10];
  const float* fnorm  = (const float*)d_in[11];

  const float betaT = powf(BETA, (float)TT);
  const int skx = 8, skout = 4;

  float* w0 = (float*)d_ws; size_t off = 0;
  auto alloc = [&](size_t n)->float*{ float* p = w0 + off; off += (n + 63) & ~(size_t)63; return p; };
  float* xa     = alloc((size_t)NT*DM);
  float* xb     = alloc((size_t)NT*DM);
  float* bfA    = alloc((size_t)NT*DI/2);       // bf16 A-matrices (xnb then ybf)
  float* xz     = alloc((size_t)NT*2*DI);
  float* xcb    = alloc((size_t)NT*DI);
  float* xdbl   = alloc((size_t)NT*XDC);
  float* dtb    = alloc((size_t)NT*DI);
  float* ylocal = alloc((size_t)NT*DI);
  float* Sbuf   = alloc((size_t)NB*CC*DI);
  float* Qg     = alloc((size_t)NB*CC*TT*256);
  float* big1   = alloc((size_t)NB*CC*NDS*DI);  // x_proj partials / Vagg / hend / out_proj partials
  float* big2   = alloc((size_t)NB*CC*NDS*DI);  // wbf / vst / hst / wbf(out)

  unsigned short* xnb = (unsigned short*)bfA;   // [NT][DM]
  unsigned short* ybf = (unsigned short*)bfA;   // [NT][DI]
  unsigned short* wbf = (unsigned short*)big2;  // bf16 weights (lifetimes disjoint from vst/hst)
  float* partb = big1;

  const float* xcur = x;
  float* nxt = xa;
  for (int l=0; l<2; l++){
    const float* inw_l = in_w   + (size_t)l*2*DI*DM;
    const float* cw_l  = conv_w + (size_t)l*DI*4;
    const float* cb_l  = conv_b + (size_t)l*DI;
    const float* xpw_l = xp_w   + (size_t)l*XDC*DI;
    const float* dtw_l = dtp_w  + (size_t)l*DI*DTR;
    const float* dtbi  = dtp_b  + (size_t)l*DI;
    const float* al_l  = A_log  + (size_t)l*DI*NDS;
    const float* d_l   = Dp     + (size_t)l*DI;
    const float* ow_l  = out_w  + (size_t)l*DM*DI;
    const float* nw_l  = norm_w + (size_t)l*DM;

    castbf_k<<<dim3((2*DI*DM/4+255)/256), dim3(256), 0, stream>>>(inw_l, wbf, 2*DI*DM/4);
    rms_k<1><<<dim3(NT), dim3(256), 0, stream>>>(xcur, nw_l, xnb);
    gemm_mf<0><<<dim3(2*DI/128, NT/128, 1), dim3(256), 0, stream>>>(
        xnb, DM, wbf, DM, xz, nullptr, NT, 2*DI, DM, 1);
    conv_k<<<dim3(DI/256, NT), dim3(256), 0, stream>>>(xz, cw_l, cb_l, xcb);
    gemm64<0><<<dim3((XDC+63)/64, NT/64, skx), dim3(256), 0, stream>>>(
        xcb, DI, xpw_l, DI, xdbl, partb, nullptr, NT, XDC, DI, skx);
    reduce_k<0><<<dim3((NT*XDC+255)/256), dim3(256), 0, stream>>>(partb, xdbl, nullptr, NT*XDC, skx);
    gemm64<1><<<dim3(DI/64, NT/64, 1), dim3(256), 0, stream>>>(
        xdbl, XDC, dtw_l, DTR, dtb, partb, dtbi, NT, DI, DTR, 1);
    vagg_k<<<dim3(DI/256, CC, NB), dim3(256), 0, stream>>>(dtb, xcb, xdbl, big1, Sbuf);
    vcomb_k<<<dim3(DI/256, NDS, NB), dim3(256), 0, stream>>>(big1, big2, betaT);
    gram_k<<<dim3(CC, NB), dim3(512), 0, stream>>>(big2, dtb, xcb, xdbl, Qg);
    apply_k<<<dim3(CC, NB, DI/256), dim3(256), 0, stream>>>(
        big2, dtb, xcb, xdbl, Qg, al_l, ylocal, big1);
    hcomb_k<<<dim3(DI/256, NDS, NB), dim3(256), 0, stream>>>(big1, Sbuf, al_l, big2);
    yepi_k<<<dim3(DI/256, NT), dim3(256), 0, stream>>>(ylocal, big2, dtb, xdbl, al_l, d_l, xcb, xz, ybf);
    castbf_k<<<dim3((DM*DI/4+255)/256), dim3(256), 0, stream>>>(ow_l, wbf, DM*DI/4);
    gemm_mf<0><<<dim3(DM/128, NT/128, skout), dim3(256), 0, stream>>>(
        ybf, DI, wbf, DI, nxt, partb, NT, DM, DI, skout);
    reduce_k<2><<<dim3((NT*DM+255)/256), dim3(256), 0, stream>>>(partb, nxt, xcur, NT*DM, skout);
    xcur = nxt; nxt = xb;
  }
  rms_k<0><<<dim3(NT), dim3(256), 0, stream>>>(xcur, fnorm, (float*)d_out);
}